// Round 1
// baseline (243.119 us; speedup 1.0000x reference)
//
#include <hip/hip_runtime.h>
#include <math.h>

#define NB 32  // NUM_BATCHES

// Workspace layout (floats):
//  [0..95]    sum1[32][3]
//  [96..127]  cnt1[32]
//  [128..223] sum2[32][3]
//  [224..319] sumsq2[32][3]
//  [320..351] cnt2[32]
#define WS_FLOATS 352

template <bool WITH_SQ>
__global__ void face_accum_kernel(const float* __restrict__ x,
                                  const int* __restrict__ b,
                                  const int* __restrict__ f,
                                  int F,
                                  float* __restrict__ gsum,
                                  float* __restrict__ gsumsq,
                                  float* __restrict__ gcnt) {
    __shared__ float ssum[NB * 3];
    __shared__ float ssq[NB * 3];
    __shared__ float scnt[NB];

    const int t = threadIdx.x;
    for (int i = t; i < NB * 3; i += blockDim.x) {
        ssum[i] = 0.0f;
        if (WITH_SQ) ssq[i] = 0.0f;
    }
    for (int i = t; i < NB; i += blockDim.x) scnt[i] = 0.0f;
    __syncthreads();

    const int stride = gridDim.x * blockDim.x;
    for (int i = blockIdx.x * blockDim.x + t; i < F; i += stride) {
        // f is [3, F]: three coalesced planes
        const int v0 = f[i];
        const int v1 = f[F + i];
        const int v2 = f[2 * F + i];

        const float ax = x[3 * v0 + 0];
        const float ay = x[3 * v0 + 1];
        const float az = x[3 * v0 + 2];
        const float e1x = x[3 * v1 + 0] - ax;
        const float e1y = x[3 * v1 + 1] - ay;
        const float e1z = x[3 * v1 + 2] - az;
        const float e2x = x[3 * v2 + 0] - ax;
        const float e2y = x[3 * v2 + 1] - ay;
        const float e2z = x[3 * v2 + 2] - az;

        // cross(e1, e2)
        float nx = e1y * e2z - e1z * e2y;
        float ny = e1z * e2x - e1x * e2z;
        float nz = e1x * e2y - e1y * e2x;
        const float inv = 1.0f / (sqrtf(nx * nx + ny * ny + nz * nz) + 1e-8f);
        nx *= inv; ny *= inv; nz *= inv;

        const int s = b[v0];  // per-face batch id from first vertex

        atomicAdd(&ssum[3 * s + 0], nx);
        atomicAdd(&ssum[3 * s + 1], ny);
        atomicAdd(&ssum[3 * s + 2], nz);
        if (WITH_SQ) {
            atomicAdd(&ssq[3 * s + 0], nx * nx);
            atomicAdd(&ssq[3 * s + 1], ny * ny);
            atomicAdd(&ssq[3 * s + 2], nz * nz);
        }
        atomicAdd(&scnt[s], 1.0f);
    }
    __syncthreads();

    for (int i = t; i < NB * 3; i += blockDim.x) {
        atomicAdd(&gsum[i], ssum[i]);
        if (WITH_SQ) atomicAdd(&gsumsq[i], ssq[i]);
    }
    for (int i = t; i < NB; i += blockDim.x) atomicAdd(&gcnt[i], scnt[i]);
}

__global__ void finalize_kernel(const float* __restrict__ ws, float* __restrict__ out) {
    const float* sum1   = ws + 0;
    const float* cnt1   = ws + 96;
    const float* sum2   = ws + 128;
    const float* sumsq2 = ws + 224;
    const float* cnt2   = ws + 320;

    const int lane = threadIdx.x;  // block of 64
    float val = 0.0f;
    if (lane < NB) {
        const float c1 = cnt1[lane];
        const float c2 = cnt2[lane];
        const float inv1 = 1.0f / c1;
        const float inv2 = 1.0f / c2;

        float m1[3], m2[3];
        float vsum = 0.0f;
        float dsum = 0.0f;
        #pragma unroll
        for (int c = 0; c < 3; ++c) {
            m1[c] = sum1[3 * lane + c] * inv1;
            m2[c] = sum2[3 * lane + c] * inv2;
            // unbiased variance: (sum(x^2) - cnt*mean^2) / (cnt - 1)
            float sq = sumsq2[3 * lane + c] - c2 * m2[c] * m2[c];
            float var = sq / (c2 - 1.0f);
            vsum += fmaxf(var, 0.0f);
            const float d = m1[c] - m2[c];
            dsum += d * d;
        }
        val = sqrtf(vsum) + sqrtf(dsum);
    }
    // wave64 reduce
    #pragma unroll
    for (int off = 32; off > 0; off >>= 1) val += __shfl_down(val, off, 64);
    if (lane == 0) out[0] = val;
}

extern "C" void kernel_launch(void* const* d_in, const int* in_sizes, int n_in,
                              void* d_out, int out_size, void* d_ws, size_t ws_size,
                              hipStream_t stream) {
    const float* x1 = (const float*)d_in[0];
    const float* x2 = (const float*)d_in[1];
    const int*   b1 = (const int*)d_in[2];
    const int*   b2 = (const int*)d_in[3];
    const int*   f1 = (const int*)d_in[4];
    const int*   f2 = (const int*)d_in[5];
    const int F1 = in_sizes[4] / 3;
    const int F2 = in_sizes[5] / 3;

    float* ws = (float*)d_ws;
    float* sum1   = ws + 0;
    float* cnt1   = ws + 96;
    float* sum2   = ws + 128;
    float* sumsq2 = ws + 224;
    float* cnt2   = ws + 320;

    hipMemsetAsync(d_ws, 0, WS_FLOATS * sizeof(float), stream);

    const int block = 256;
    const int grid1 = min((F1 + block - 1) / block, 2048);
    const int grid2 = min((F2 + block - 1) / block, 2048);

    face_accum_kernel<false><<<grid1, block, 0, stream>>>(x1, b1, f1, F1, sum1, nullptr, cnt1);
    face_accum_kernel<true ><<<grid2, block, 0, stream>>>(x2, b2, f2, F2, sum2, sumsq2, cnt2);
    finalize_kernel<<<1, 64, 0, stream>>>(ws, (float*)d_out);
}